// Round 6
// baseline (707.273 us; speedup 1.0000x reference)
//
#include <hip/hip_runtime.h>

#define BATCH 4
#define CDIM 256
#define NDIM 4096
#define SPLITS 4
#define KSPLIT (NDIM / SPLITS)   // 1024 keys per split
#define JT 32                    // keys per j-tile
#define NTILES (KSPLIT / JT)     // 32

typedef unsigned short u16;
typedef unsigned int u32;
typedef _Float16 f16;
typedef __attribute__((ext_vector_type(8))) _Float16 half8;
typedef __attribute__((ext_vector_type(4))) float floatx4;

__device__ __forceinline__ void load_lds_128(const void* g, void* l) {
  __builtin_amdgcn_global_load_lds(
      (const __attribute__((address_space(1))) u32*)g,
      (__attribute__((address_space(3))) u32*)l, 16, 0, 0);
}

// ---------------------------------------------------------------------------
// W (f32 [C][C]) -> fp16 [C][C], rows stay contraction-contiguous.
// ---------------------------------------------------------------------------
__global__ __launch_bounds__(256) void prep_w_k(
    const float* __restrict__ wq, const float* __restrict__ wk,
    const float* __restrict__ wv, f16* __restrict__ whq,
    f16* __restrict__ whk, f16* __restrict__ whv) {
  const int gid = blockIdx.x * 256 + threadIdx.x;  // 0..24575
  const int a = gid >> 13;
  const int r = gid & 8191;
  const float* src = (a == 0) ? wq : ((a == 1) ? wk : wv);
  f16* dst = (a == 0) ? whq : ((a == 1) ? whk : whv);
  float4 v0 = *(const float4*)(src + r * 8);
  float4 v1 = *(const float4*)(src + r * 8 + 4);
  half8 h;
  h[0] = (f16)v0.x; h[1] = (f16)v0.y; h[2] = (f16)v0.z; h[3] = (f16)v0.w;
  h[4] = (f16)v1.x; h[5] = (f16)v1.y; h[6] = (f16)v1.z; h[7] = (f16)v1.w;
  *(half8*)(dst + r * 8) = h;
}

// ---------------------------------------------------------------------------
// x f32 [B][C][N] -> xt fp16 [B][N][C].  grid (N/64, C/64, 2*B), block 256.
// ---------------------------------------------------------------------------
__global__ __launch_bounds__(256) void transpose_k(
    const float* __restrict__ x1, const float* __restrict__ x2,
    f16* __restrict__ xt1, f16* __restrict__ xt2) {
  __shared__ __align__(16) float tile[64 * 68];
  const int z = blockIdx.z;
  const float* src = (z & 1) ? x2 : x1;
  f16* dst = (z & 1) ? xt2 : xt1;
  const int b = z >> 1;
  src += (size_t)b * CDIM * NDIM;
  dst += (size_t)b * NDIM * CDIM;
  const int n0 = blockIdx.x * 64, c0 = blockIdx.y * 64;
  const int t = threadIdx.x;
#pragma unroll
  for (int it = 0; it < 4; ++it) {
    int chunk = t + it * 256;
    int row = chunk >> 4;
    int col4 = (chunk & 15) << 2;
    float4 v = *(const float4*)(src + (size_t)(c0 + row) * NDIM + (n0 + col4));
    *(float4*)&tile[row * 68 + col4] = v;
  }
  __syncthreads();
#pragma unroll
  for (int it = 0; it < 2; ++it) {
    int task = t + it * 256;
    int nl = task >> 3;
    int cb = (task & 7) << 3;
    half8 h;
#pragma unroll
    for (int j = 0; j < 8; ++j) h[j] = (f16)tile[(cb + j) * 68 + nl];
    *(half8*)(dst + (size_t)(n0 + nl) * CDIM + (c0 + cb)) = h;
  }
}

// ---------------------------------------------------------------------------
// Qt[b][i][c] = sum_c' Xt[b][i][c'] * W[c][c'] + bias[c]  (also Kt)
// ---------------------------------------------------------------------------
__global__ __launch_bounds__(256, 2) void proj_qk_k(
    const f16* __restrict__ xt1, const f16* __restrict__ xt2,
    const f16* __restrict__ whq, const float* __restrict__ bq,
    const f16* __restrict__ whk, const float* __restrict__ bk,
    f16* __restrict__ qt, f16* __restrict__ kt) {
  const int z = blockIdx.z;
  const int which = z & 1, b = z >> 1;
  const f16* xt = which ? xt2 : xt1;
  const f16* w = which ? whk : whq;
  const float* bias = which ? bk : bq;
  f16* outp = which ? kt : qt;
  xt += (size_t)b * NDIM * CDIM;
  outp += (size_t)b * NDIM * CDIM;
  const int c0 = blockIdx.x * 128, i0 = blockIdx.y * 128;
  const int tid = threadIdx.x;
  const int wave = tid >> 6, lane = tid & 63, l16 = lane & 15, grp = lane >> 4;
  const int wi = (wave & 1) * 64, wc = (wave >> 1) * 64;
  floatx4 acc[4][4];
#pragma unroll
  for (int mb = 0; mb < 4; ++mb)
#pragma unroll
    for (int nb = 0; nb < 4; ++nb) acc[mb][nb] = (floatx4){0.f, 0.f, 0.f, 0.f};
#pragma unroll
  for (int ks = 0; ks < 8; ++ks) {
    const int kofs = ks * 32 + grp * 8;
    half8 a[4], bb[4];
#pragma unroll
    for (int mb = 0; mb < 4; ++mb)
      a[mb] = *(const half8*)(xt + (size_t)(i0 + wi + mb * 16 + l16) * CDIM + kofs);
#pragma unroll
    for (int nb = 0; nb < 4; ++nb)
      bb[nb] = *(const half8*)(w + (size_t)(c0 + wc + nb * 16 + l16) * CDIM + kofs);
#pragma unroll
    for (int mb = 0; mb < 4; ++mb)
#pragma unroll
      for (int nb = 0; nb < 4; ++nb)
        acc[mb][nb] = __builtin_amdgcn_mfma_f32_16x16x32_f16(a[mb], bb[nb], acc[mb][nb], 0, 0, 0);
  }
#pragma unroll
  for (int nb = 0; nb < 4; ++nb) {
    const int c = c0 + wc + nb * 16 + l16;
    const float bv = bias[c];
#pragma unroll
    for (int mb = 0; mb < 4; ++mb) {
      const int ibase = i0 + wi + mb * 16 + grp * 4;
#pragma unroll
      for (int r = 0; r < 4; ++r)
        outp[(size_t)(ibase + r) * CDIM + c] = (f16)(acc[mb][nb][r] + bv);
    }
  }
}

// ---------------------------------------------------------------------------
// Vs[b][c][j] = sum_c' Wv[c][c'] * Xt2[b][j][c'] + bv[c]
// ---------------------------------------------------------------------------
__global__ __launch_bounds__(256, 2) void proj_v_k(
    const f16* __restrict__ xt2, const f16* __restrict__ whv,
    const float* __restrict__ bv, f16* __restrict__ vsout) {
  const int b = blockIdx.z;
  const f16* xt = xt2 + (size_t)b * NDIM * CDIM;
  f16* outp = vsout + (size_t)b * CDIM * NDIM;
  const int c0 = blockIdx.x * 128, j0 = blockIdx.y * 128;
  const int tid = threadIdx.x;
  const int wave = tid >> 6, lane = tid & 63, l16 = lane & 15, grp = lane >> 4;
  const int wc = (wave & 1) * 64, wj = (wave >> 1) * 64;
  floatx4 acc[4][4];
#pragma unroll
  for (int mb = 0; mb < 4; ++mb)
#pragma unroll
    for (int nb = 0; nb < 4; ++nb) acc[mb][nb] = (floatx4){0.f, 0.f, 0.f, 0.f};
#pragma unroll
  for (int ks = 0; ks < 8; ++ks) {
    const int kofs = ks * 32 + grp * 8;
    half8 a[4], bb[4];
#pragma unroll
    for (int mb = 0; mb < 4; ++mb)
      a[mb] = *(const half8*)(whv + (size_t)(c0 + wc + mb * 16 + l16) * CDIM + kofs);
#pragma unroll
    for (int nb = 0; nb < 4; ++nb)
      bb[nb] = *(const half8*)(xt + (size_t)(j0 + wj + nb * 16 + l16) * CDIM + kofs);
#pragma unroll
    for (int mb = 0; mb < 4; ++mb)
#pragma unroll
      for (int nb = 0; nb < 4; ++nb)
        acc[mb][nb] = __builtin_amdgcn_mfma_f32_16x16x32_f16(a[mb], bb[nb], acc[mb][nb], 0, 0, 0);
  }
#pragma unroll
  for (int mb = 0; mb < 4; ++mb)
#pragma unroll
    for (int r = 0; r < 4; ++r) {
      const int c = c0 + wc + mb * 16 + grp * 4 + r;
      const float bvv = bv[c];
#pragma unroll
      for (int nb = 0; nb < 4; ++nb) {
        const int j = j0 + wj + nb * 16 + l16;
        outp[(size_t)c * NDIM + j] = (f16)(acc[mb][nb][r] + bvv);
      }
    }
}

// ---------------------------------------------------------------------------
// Flash attention partial, 64 q/wave (4 m-blocks), 256 q/block, JT=32.
// Grid 256 = 16 q-tiles x (4 b x 4 split); 1 block/CU, 1 wave/SIMD,
// __launch_bounds__(256,1) -> 512-VGPR regime (peak live ~400, no spill).
// LDS 102400 B: dbuf K/V 2x32KB + P (f32, 64x36/wave) 36.9KB.
// Single barrier/tile; K/V prefetch issued right after it (full compute
// phase in flight before the next barrier's vmcnt drain).
// Q-fragments re-read from L2 each tile in two k-halves (TA pipe, not DS).
// ---------------------------------------------------------------------------
__global__ __launch_bounds__(256, 1) void flash_k(
    const f16* __restrict__ qt, const f16* __restrict__ kt,
    const f16* __restrict__ vs, f16* __restrict__ pO,
    float* __restrict__ pm, float* __restrict__ pl) {
  __shared__ __align__(16) u16 smem[51200];  // 102400 B
  const int bx = blockIdx.x;
  const int c16 = bx & 15;                   // XCD-pinned (b,s)
  const int b = c16 >> 2, s = c16 & 3;
  const int i0 = (bx >> 4) * 256;
  const int jwin = s * KSPLIT;
  const f16* K = kt + (size_t)b * NDIM * CDIM;
  const f16* V = vs + (size_t)b * CDIM * NDIM;
  const int tid = threadIdx.x;
  const int wave = tid >> 6, lane = tid & 63, l16 = lane & 15, grp = lane >> 4;
  const int wq = wave * 64;
  // per-lane Q gather base: row i0+wq+l16, col grp*8
  const f16* Qw = qt + (size_t)b * NDIM * CDIM + (size_t)(i0 + wq + l16) * CDIM + grp * 8;

  float* Pw = (float*)(smem + 32768) + wave * (64 * 36);  // 64 rows x 36 f32

  floatx4 O[4][16];
#pragma unroll
  for (int mb = 0; mb < 4; ++mb)
#pragma unroll
    for (int cb = 0; cb < 16; ++cb) O[mb][cb] = (floatx4){0.f, 0.f, 0.f, 0.f};
  float m_[4][4], lsum[4][4];
#pragma unroll
  for (int mb = 0; mb < 4; ++mb)
#pragma unroll
    for (int r = 0; r < 4; ++r) { m_[mb][r] = -1e30f; lsum[mb][r] = 0.f; }

  const int kr2 = lane >> 5, kp = lane & 31;   // K staging: 2 rows/instr
  const int vrow = lane >> 2, vp = lane & 3;   // V staging: 16 rows/instr

#define STAGE(J0, BUF)                                                         \
  {                                                                            \
    u16* sK = smem + (BUF) * 16384;                                            \
    u16* sV = sK + 8192;                                                       \
    _Pragma("unroll") for (int it = 0; it < 4; ++it) {                         \
      const int row = wave * 8 + it * 2 + kr2;                                 \
      const int g = kp ^ (row & 7);                                            \
      load_lds_128(K + (size_t)((J0) + row) * CDIM + g * 8,                    \
                   &sK[(wave * 8 + it * 2) * 256]);                            \
    }                                                                          \
    _Pragma("unroll") for (int it = 0; it < 4; ++it) {                         \
      const int c = wave * 64 + it * 16 + vrow;                                \
      const int g = vp ^ ((c >> 2) & 3);                                       \
      load_lds_128(V + (size_t)c * NDIM + (J0) + g * 8,                        \
                   &sV[(wave * 64 + it * 16) * 32]);                           \
    }                                                                          \
  }

  STAGE(jwin, 0)

  for (int tt = 0; tt < NTILES; ++tt) {
    u16* bK = smem + (tt & 1) * 16384;
    u16* bV = bK + 8192;
    __syncthreads();  // drains prefetch(tt) (in flight during compute of tt-1)
    if (tt + 1 < NTILES) STAGE(jwin + (tt + 1) * JT, (tt + 1) & 1)

    // ---- S = Q K^T : 64 q x 32 keys/wave, kf shared across 4 m-blocks ----
    floatx4 S[4][2];
#pragma unroll
    for (int mb = 0; mb < 4; ++mb)
#pragma unroll
      for (int jb = 0; jb < 2; ++jb) S[mb][jb] = (floatx4){0.f, 0.f, 0.f, 0.f};
#pragma unroll
    for (int half = 0; half < 2; ++half) {
      half8 qh[4][4];  // transient: 64 VGPRs per half
#pragma unroll
      for (int mb = 0; mb < 4; ++mb)
#pragma unroll
        for (int kk = 0; kk < 4; ++kk)
          qh[mb][kk] = *(const half8*)(Qw + (size_t)(mb * 16) * CDIM + (half * 4 + kk) * 32);
#pragma unroll
      for (int kk = 0; kk < 4; ++kk) {
        const int chunk = (half * 4 + kk) * 4 + grp;
#pragma unroll
        for (int jb = 0; jb < 2; ++jb) {
          const int row = jb * 16 + l16;
          half8 kf = *(const half8*)&bK[row * 256 + ((chunk ^ (row & 7)) << 3)];
#pragma unroll
          for (int mb = 0; mb < 4; ++mb)
            S[mb][jb] = __builtin_amdgcn_mfma_f32_16x16x32_f16(qh[mb][kk], kf, S[mb][jb], 0, 0, 0);
        }
      }
    }

    // ---- softmax per m-block: in-loop max reduce only; l deferred ----
#pragma unroll
    for (int mb = 0; mb < 4; ++mb) {
      float mnew[4];
#pragma unroll
      for (int r = 0; r < 4; ++r) mnew[r] = fmaxf(S[mb][0][r], S[mb][1][r]);
#pragma unroll
      for (int mask = 1; mask < 16; mask <<= 1)
#pragma unroll
        for (int r = 0; r < 4; ++r) mnew[r] = fmaxf(mnew[r], __shfl_xor(mnew[r], mask, 64));
      bool upd = false;
#pragma unroll
      for (int r = 0; r < 4; ++r) upd = upd || (mnew[r] > m_[mb][r]);
      if (__any(upd)) {  // rescale only when some row's max moved
        float alpha[4];
#pragma unroll
        for (int r = 0; r < 4; ++r) {
          const float mt = fmaxf(m_[mb][r], mnew[r]);
          alpha[r] = __expf(m_[mb][r] - mt);
          m_[mb][r] = mt;
          lsum[mb][r] *= alpha[r];
        }
#pragma unroll
        for (int cb = 0; cb < 16; ++cb)
#pragma unroll
          for (int r = 0; r < 4; ++r) O[mb][cb][r] *= alpha[r];
      }
#pragma unroll
      for (int r = 0; r < 4; ++r) {
        S[mb][0][r] = __expf(S[mb][0][r] - m_[mb][r]);
        S[mb][1][r] = __expf(S[mb][1][r] - m_[mb][r]);
        lsum[mb][r] += S[mb][0][r] + S[mb][1][r];  // per-lane partial (16 cols)
      }
      // P write: C-layout -> wave-private f32 LDS (stride 36)
#pragma unroll
      for (int jb = 0; jb < 2; ++jb)
#pragma unroll
        for (int r = 0; r < 4; ++r)
          Pw[(mb * 16 + grp * 4 + r) * 36 + jb * 16 + l16] = S[mb][jb][r];
    }

    // ---- pa: A-operand frags from P ----
    half8 pa[4];
#pragma unroll
    for (int mb = 0; mb < 4; ++mb) {
      floatx4 u0 = *(const floatx4*)&Pw[(mb * 16 + l16) * 36 + grp * 8];
      floatx4 u1 = *(const floatx4*)&Pw[(mb * 16 + l16) * 36 + grp * 8 + 4];
      half8 h;
      h[0] = (f16)u0[0]; h[1] = (f16)u0[1]; h[2] = (f16)u0[2]; h[3] = (f16)u0[3];
      h[4] = (f16)u1[0]; h[5] = (f16)u1[1]; h[6] = (f16)u1[2]; h[7] = (f16)u1[3];
      pa[mb] = h;
    }

    // ---- O += P V : vf shared across 4 m-blocks ----
#pragma unroll
    for (int cb = 0; cb < 16; ++cb) {
      const int c = cb * 16 + l16;
      half8 vf = *(const half8*)&bV[c * 32 + ((grp ^ ((c >> 2) & 3)) << 3)];
#pragma unroll
      for (int mb = 0; mb < 4; ++mb)
        O[mb][cb] = __builtin_amdgcn_mfma_f32_16x16x32_f16(pa[mb], vf, O[mb][cb], 0, 0, 0);
    }
  }

  // ---- final l reduce across the 16 column-lanes ----
#pragma unroll
  for (int mask = 1; mask < 16; mask <<= 1)
#pragma unroll
    for (int mb = 0; mb < 4; ++mb)
#pragma unroll
      for (int r = 0; r < 4; ++r) lsum[mb][r] += __shfl_xor(lsum[mb][r], mask, 64);
  if (l16 == 0) {
    const int base = (b * SPLITS + s) * NDIM + i0;
#pragma unroll
    for (int mb = 0; mb < 4; ++mb)
#pragma unroll
      for (int r = 0; r < 4; ++r) {
        const int i = wq + mb * 16 + grp * 4 + r;
        pm[base + i] = m_[mb][r];
        pl[base + i] = lsum[mb][r];
      }
  }

  // ---- epilogue: pO[(b*4+s)][c][i0..i0+255] f16, 4 channel-quarters ----
  // sO: 64 channels x stride 260 f32 (>=256 queries, rows 16B-aligned)
#pragma unroll
  for (int quarter = 0; quarter < 4; ++quarter) {
    __syncthreads();
    float* sO = (float*)smem;  // 64 x 260 x 4B = 66560 B <= 102400 B
#pragma unroll
    for (int mb = 0; mb < 4; ++mb)
#pragma unroll
      for (int cb4 = 0; cb4 < 4; ++cb4) {
        const int cb = quarter * 4 + cb4;
        const int cl = cb4 * 16 + l16;
        const int i = wq + mb * 16 + grp * 4;
        *(floatx4*)&sO[cl * 260 + i] = O[mb][cb];
      }
    __syncthreads();
    const size_t obase = ((size_t)(b * SPLITS + s) * CDIM + quarter * 64) * NDIM + i0;
#pragma unroll
    for (int it = 0; it < 8; ++it) {
      const int task = tid + it * 256;   // 0..2047 = 64 ch x 32 q-chunks of 8
      const int cl = task >> 5, p = (task & 31) * 8;
      floatx4 v0 = *(const floatx4*)&sO[cl * 260 + p];
      floatx4 v1 = *(const floatx4*)&sO[cl * 260 + p + 4];
      half8 h;
      h[0] = (f16)v0[0]; h[1] = (f16)v0[1]; h[2] = (f16)v0[2]; h[3] = (f16)v0[3];
      h[4] = (f16)v1[0]; h[5] = (f16)v1[1]; h[6] = (f16)v1[2]; h[7] = (f16)v1[3];
      *(half8*)(pO + obase + (size_t)cl * NDIM + p) = h;
    }
  }
}

// ---------------------------------------------------------------------------
// Combine 4 split partials: out[b][c][i] = sum_s u_s(i) * O_s[c][i]
// ---------------------------------------------------------------------------
__global__ __launch_bounds__(256) void combine_k(
    const f16* __restrict__ pO, const float* __restrict__ pm,
    const float* __restrict__ pl, float* __restrict__ out) {
  __shared__ float su[SPLITS][64];
  const int b = blockIdx.x >> 6;
  const int i0 = (blockIdx.x & 63) * 64;
  const int t = threadIdx.x;
  if (t < 64) {
    const int i = i0 + t;
    float mv[SPLITS], w[SPLITS];
    float M = -3e38f;
#pragma unroll
    for (int s = 0; s < SPLITS; ++s) {
      mv[s] = pm[(b * SPLITS + s) * NDIM + i];
      M = fmaxf(M, mv[s]);
    }
    float L = 0.f;
#pragma unroll
    for (int s = 0; s < SPLITS; ++s) {
      w[s] = __expf(mv[s] - M);
      L += pl[(b * SPLITS + s) * NDIM + i] * w[s];
    }
    const float invL = 1.0f / L;
#pragma unroll
    for (int s = 0; s < SPLITS; ++s) su[s][t] = w[s] * invL;
  }
  __syncthreads();
#pragma unroll
  for (int it = 0; it < 8; ++it) {
    const int task = t + it * 256;
    const int c = task >> 3, p = (task & 7) * 8;
    float acc[8] = {0.f, 0.f, 0.f, 0.f, 0.f, 0.f, 0.f, 0.f};
#pragma unroll
    for (int s = 0; s < SPLITS; ++s) {
      const f16* src = pO + ((size_t)(b * SPLITS + s) * CDIM + c) * NDIM + i0 + p;
      half8 h = *(const half8*)src;
#pragma unroll
      for (int j = 0; j < 8; ++j) acc[j] += su[s][p + j] * (float)h[j];
    }
    float* dst = out + ((size_t)b * CDIM + c) * NDIM + i0 + p;
    float4 lo = {acc[0], acc[1], acc[2], acc[3]};
    float4 hi = {acc[4], acc[5], acc[6], acc[7]};
    *(float4*)dst = lo;
    *(float4*)(dst + 4) = hi;
  }
}

// ---------------------------------------------------------------------------
extern "C" void kernel_launch(void* const* d_in, const int* in_sizes, int n_in,
                              void* d_out, int out_size, void* d_ws, size_t ws_size,
                              hipStream_t stream) {
  const float* x1 = (const float*)d_in[0];
  const float* x2 = (const float*)d_in[1];
  const float* Wq = (const float*)d_in[2];
  const float* bq = (const float*)d_in[3];
  const float* Wk = (const float*)d_in[4];
  const float* bk = (const float*)d_in[5];
  const float* Wv = (const float*)d_in[6];
  const float* bv = (const float*)d_in[7];
  float* out = (float*)d_out;
  char* ws = (char*)d_ws;
  // 8 MB each
  f16* qtp = (f16*)(ws + 0);
  f16* ktp = (f16*)(ws + 8388608);
  f16* vsp = (f16*)(ws + 16777216);
  f16* xt1 = (f16*)(ws + 25165824);
  f16* xt2 = (f16*)(ws + 33554432);
  f16* whq = (f16*)(ws + 41943040);
  f16* whk = whq + CDIM * CDIM;
  f16* whv = whk + CDIM * CDIM;
  // pO (32 MB) overlays xt1/xt2/wh (dead after proj kernels)
  f16* pO = (f16*)(ws + 25165824);
  float* pm = (float*)(ws + 58720256);
  float* pl = (float*)(ws + 58982400);

  prep_w_k<<<dim3(96), dim3(256), 0, stream>>>(Wq, Wk, Wv, whq, whk, whv);
  transpose_k<<<dim3(NDIM / 64, CDIM / 64, 2 * BATCH), dim3(256), 0, stream>>>(x1, x2, xt1, xt2);
  proj_qk_k<<<dim3(2, 32, 2 * BATCH), dim3(256), 0, stream>>>(xt1, xt2, whq, bq, whk, bk, qtp, ktp);
  proj_v_k<<<dim3(2, 32, BATCH), dim3(256), 0, stream>>>(xt2, whv, bv, vsp);
  flash_k<<<dim3(256), dim3(256), 0, stream>>>(qtp, ktp, vsp, pO, pm, pl);
  combine_k<<<dim3(256), dim3(256), 0, stream>>>(pO, pm, pl, out);
}

// Round 7
// 261.927 us; speedup vs baseline: 2.7003x; 2.7003x over previous
//
#include <hip/hip_runtime.h>

#define BATCH 4
#define CDIM 256
#define NDIM 4096
#define SPLITS 4
#define KSPLIT (NDIM / SPLITS)   // 1024 keys per split
#define JT 32                    // keys per j-tile
#define NTILES (KSPLIT / JT)     // 32

typedef unsigned short u16;
typedef unsigned int u32;
typedef _Float16 f16;
typedef __attribute__((ext_vector_type(8))) _Float16 half8;
typedef __attribute__((ext_vector_type(4))) float floatx4;

__device__ __forceinline__ void load_lds_128(const void* g, void* l) {
  __builtin_amdgcn_global_load_lds(
      (const __attribute__((address_space(1))) u32*)g,
      (__attribute__((address_space(3))) u32*)l, 16, 0, 0);
}

// ---------------------------------------------------------------------------
// W (f32 [C][C]) -> fp16 [C][C], rows stay contraction-contiguous.
// ---------------------------------------------------------------------------
__global__ __launch_bounds__(256) void prep_w_k(
    const float* __restrict__ wq, const float* __restrict__ wk,
    const float* __restrict__ wv, f16* __restrict__ whq,
    f16* __restrict__ whk, f16* __restrict__ whv) {
  const int gid = blockIdx.x * 256 + threadIdx.x;  // 0..24575
  const int a = gid >> 13;
  const int r = gid & 8191;
  const float* src = (a == 0) ? wq : ((a == 1) ? wk : wv);
  f16* dst = (a == 0) ? whq : ((a == 1) ? whk : whv);
  float4 v0 = *(const float4*)(src + r * 8);
  float4 v1 = *(const float4*)(src + r * 8 + 4);
  half8 h;
  h[0] = (f16)v0.x; h[1] = (f16)v0.y; h[2] = (f16)v0.z; h[3] = (f16)v0.w;
  h[4] = (f16)v1.x; h[5] = (f16)v1.y; h[6] = (f16)v1.z; h[7] = (f16)v1.w;
  *(half8*)(dst + r * 8) = h;
}

// ---------------------------------------------------------------------------
// x f32 [B][C][N] -> xt fp16 [B][N][C].  grid (N/64, C/64, 2*B), block 256.
// ---------------------------------------------------------------------------
__global__ __launch_bounds__(256) void transpose_k(
    const float* __restrict__ x1, const float* __restrict__ x2,
    f16* __restrict__ xt1, f16* __restrict__ xt2) {
  __shared__ __align__(16) float tile[64 * 68];
  const int z = blockIdx.z;
  const float* src = (z & 1) ? x2 : x1;
  f16* dst = (z & 1) ? xt2 : xt1;
  const int b = z >> 1;
  src += (size_t)b * CDIM * NDIM;
  dst += (size_t)b * NDIM * CDIM;
  const int n0 = blockIdx.x * 64, c0 = blockIdx.y * 64;
  const int t = threadIdx.x;
#pragma unroll
  for (int it = 0; it < 4; ++it) {
    int chunk = t + it * 256;
    int row = chunk >> 4;
    int col4 = (chunk & 15) << 2;
    float4 v = *(const float4*)(src + (size_t)(c0 + row) * NDIM + (n0 + col4));
    *(float4*)&tile[row * 68 + col4] = v;
  }
  __syncthreads();
#pragma unroll
  for (int it = 0; it < 2; ++it) {
    int task = t + it * 256;
    int nl = task >> 3;
    int cb = (task & 7) << 3;
    half8 h;
#pragma unroll
    for (int j = 0; j < 8; ++j) h[j] = (f16)tile[(cb + j) * 68 + nl];
    *(half8*)(dst + (size_t)(n0 + nl) * CDIM + (c0 + cb)) = h;
  }
}

// ---------------------------------------------------------------------------
// Qt[b][i][c] = sum_c' Xt[b][i][c'] * W[c][c'] + bias[c]  (also Kt)
// ---------------------------------------------------------------------------
__global__ __launch_bounds__(256, 2) void proj_qk_k(
    const f16* __restrict__ xt1, const f16* __restrict__ xt2,
    const f16* __restrict__ whq, const float* __restrict__ bq,
    const f16* __restrict__ whk, const float* __restrict__ bk,
    f16* __restrict__ qt, f16* __restrict__ kt) {
  const int z = blockIdx.z;
  const int which = z & 1, b = z >> 1;
  const f16* xt = which ? xt2 : xt1;
  const f16* w = which ? whk : whq;
  const float* bias = which ? bk : bq;
  f16* outp = which ? kt : qt;
  xt += (size_t)b * NDIM * CDIM;
  outp += (size_t)b * NDIM * CDIM;
  const int c0 = blockIdx.x * 128, i0 = blockIdx.y * 128;
  const int tid = threadIdx.x;
  const int wave = tid >> 6, lane = tid & 63, l16 = lane & 15, grp = lane >> 4;
  const int wi = (wave & 1) * 64, wc = (wave >> 1) * 64;
  floatx4 acc[4][4];
#pragma unroll
  for (int mb = 0; mb < 4; ++mb)
#pragma unroll
    for (int nb = 0; nb < 4; ++nb) acc[mb][nb] = (floatx4){0.f, 0.f, 0.f, 0.f};
#pragma unroll
  for (int ks = 0; ks < 8; ++ks) {
    const int kofs = ks * 32 + grp * 8;
    half8 a[4], bb[4];
#pragma unroll
    for (int mb = 0; mb < 4; ++mb)
      a[mb] = *(const half8*)(xt + (size_t)(i0 + wi + mb * 16 + l16) * CDIM + kofs);
#pragma unroll
    for (int nb = 0; nb < 4; ++nb)
      bb[nb] = *(const half8*)(w + (size_t)(c0 + wc + nb * 16 + l16) * CDIM + kofs);
#pragma unroll
    for (int mb = 0; mb < 4; ++mb)
#pragma unroll
      for (int nb = 0; nb < 4; ++nb)
        acc[mb][nb] = __builtin_amdgcn_mfma_f32_16x16x32_f16(a[mb], bb[nb], acc[mb][nb], 0, 0, 0);
  }
#pragma unroll
  for (int nb = 0; nb < 4; ++nb) {
    const int c = c0 + wc + nb * 16 + l16;
    const float bv = bias[c];
#pragma unroll
    for (int mb = 0; mb < 4; ++mb) {
      const int ibase = i0 + wi + mb * 16 + grp * 4;
#pragma unroll
      for (int r = 0; r < 4; ++r)
        outp[(size_t)(ibase + r) * CDIM + c] = (f16)(acc[mb][nb][r] + bv);
    }
  }
}

// ---------------------------------------------------------------------------
// Vs[b][c][j] = sum_c' Wv[c][c'] * Xt2[b][j][c'] + bv[c]
// ---------------------------------------------------------------------------
__global__ __launch_bounds__(256, 2) void proj_v_k(
    const f16* __restrict__ xt2, const f16* __restrict__ whv,
    const float* __restrict__ bv, f16* __restrict__ vsout) {
  const int b = blockIdx.z;
  const f16* xt = xt2 + (size_t)b * NDIM * CDIM;
  f16* outp = vsout + (size_t)b * CDIM * NDIM;
  const int c0 = blockIdx.x * 128, j0 = blockIdx.y * 128;
  const int tid = threadIdx.x;
  const int wave = tid >> 6, lane = tid & 63, l16 = lane & 15, grp = lane >> 4;
  const int wc = (wave & 1) * 64, wj = (wave >> 1) * 64;
  floatx4 acc[4][4];
#pragma unroll
  for (int mb = 0; mb < 4; ++mb)
#pragma unroll
    for (int nb = 0; nb < 4; ++nb) acc[mb][nb] = (floatx4){0.f, 0.f, 0.f, 0.f};
#pragma unroll
  for (int ks = 0; ks < 8; ++ks) {
    const int kofs = ks * 32 + grp * 8;
    half8 a[4], bb[4];
#pragma unroll
    for (int mb = 0; mb < 4; ++mb)
      a[mb] = *(const half8*)(whv + (size_t)(c0 + wc + mb * 16 + l16) * CDIM + kofs);
#pragma unroll
    for (int nb = 0; nb < 4; ++nb)
      bb[nb] = *(const half8*)(xt + (size_t)(j0 + wj + nb * 16 + l16) * CDIM + kofs);
#pragma unroll
    for (int mb = 0; mb < 4; ++mb)
#pragma unroll
      for (int nb = 0; nb < 4; ++nb)
        acc[mb][nb] = __builtin_amdgcn_mfma_f32_16x16x32_f16(a[mb], bb[nb], acc[mb][nb], 0, 0, 0);
  }
#pragma unroll
  for (int mb = 0; mb < 4; ++mb)
#pragma unroll
    for (int r = 0; r < 4; ++r) {
      const int c = c0 + wc + mb * 16 + grp * 4 + r;
      const float bvv = bv[c];
#pragma unroll
      for (int nb = 0; nb < 4; ++nb) {
        const int j = j0 + wj + nb * 16 + l16;
        outp[(size_t)c * NDIM + j] = (f16)(acc[mb][nb][r] + bvv);
      }
    }
}

// ---------------------------------------------------------------------------
// Flash attention partial, round-7 interior:
//  - raw-S LDS roundtrip: row stats computed in A-layout (in-lane tree +
//    xor16/xor32 shuffles only)
//  - PV transposed: O^T[c][i]; alpha per-lane (l16=query); direct epilogue
//  - K/V double-buffered, ONE barrier per tile, prefetch-after-barrier
// Grid 512 = 32 q-tiles x (4 b x 4 split); 4 waves, 32 q/wave, 2 blocks/CU.
// LDS: dbuf 2x32 KB + P 16x36 f32/wave = 73.75 KB.
// ---------------------------------------------------------------------------
__global__ __launch_bounds__(256, 2) void flash_k(
    const f16* __restrict__ qt, const f16* __restrict__ kt,
    const f16* __restrict__ vs, f16* __restrict__ pO,
    float* __restrict__ pm, float* __restrict__ pl) {
  __shared__ __align__(16) u16 smem[32768 + 4608];  // 64 KB dbuf + 9216 B P
  const int bx = blockIdx.x;
  const int c16 = bx & 15;                   // XCD-pinned (b,s)
  const int b = c16 >> 2, s = c16 & 3;
  const int i0 = (bx >> 4) * 128;
  const int jwin = s * KSPLIT;
  const f16* Q = qt + (size_t)b * NDIM * CDIM;
  const f16* K = kt + (size_t)b * NDIM * CDIM;
  const f16* V = vs + (size_t)b * CDIM * NDIM;
  const int tid = threadIdx.x;
  const int wave = tid >> 6, lane = tid & 63, l16 = lane & 15, grp = lane >> 4;
  float* Pw = (float*)(smem + 32768) + wave * (16 * 36);  // 16 rows x 36 f32

  // persistent Q frags: 2 m-blocks of 16 q
  half8 qf[2][8];
#pragma unroll
  for (int mb = 0; mb < 2; ++mb)
#pragma unroll
    for (int ks = 0; ks < 8; ++ks)
      qf[mb][ks] = *(const half8*)(Q + (size_t)(i0 + wave * 32 + mb * 16 + l16) * CDIM +
                                   ks * 32 + grp * 8);

  floatx4 O[2][16];  // O^T: [mb][cb]: row=channel-local grp*4+r, col=query l16
#pragma unroll
  for (int mb = 0; mb < 2; ++mb)
#pragma unroll
    for (int cb = 0; cb < 16; ++cb) O[mb][cb] = (floatx4){0.f, 0.f, 0.f, 0.f};
  float m_[2] = {-1e30f, -1e30f};   // per-lane: query row l16 of m-block mb
  float lsum[2] = {0.f, 0.f};       // per-lane partial over this lane's 8 cols

  const int kr2 = lane >> 5, kp = lane & 31;   // K staging: 2 rows/instr
  const int vrow = lane >> 2, vp = lane & 3;   // V staging: 16 rows/instr

#define STAGE(J0, BUF)                                                         \
  {                                                                            \
    u16* sK = smem + (BUF) * 16384;                                            \
    u16* sV = sK + 8192;                                                       \
    _Pragma("unroll") for (int it = 0; it < 4; ++it) {                         \
      const int row = wave * 8 + it * 2 + kr2;                                 \
      const int g = kp ^ (row & 7);                                            \
      load_lds_128(K + (size_t)((J0) + row) * CDIM + g * 8,                    \
                   &sK[(wave * 8 + it * 2) * 256]);                            \
    }                                                                          \
    _Pragma("unroll") for (int it = 0; it < 4; ++it) {                         \
      const int c = wave * 64 + it * 16 + vrow;                                \
      const int g = vp ^ ((c >> 2) & 3);                                       \
      load_lds_128(V + (size_t)c * NDIM + (J0) + g * 8,                        \
                   &sV[(wave * 64 + it * 16) * 32]);                           \
    }                                                                          \
  }

  STAGE(jwin, 0)

  for (int tt = 0; tt < NTILES; ++tt) {
    __syncthreads();  // drains prefetch(tt); frees buffer (tt+1)&1 for prefetch
    if (tt + 1 < NTILES) STAGE(jwin + (tt + 1) * JT, (tt + 1) & 1)
    u16* bK = smem + (tt & 1) * 16384;
    u16* bV = bK + 8192;

    // ---- S = Q K^T (C-layout: row=query grp*4+r, col=key l16) ----
    floatx4 S[2][2];
#pragma unroll
    for (int mb = 0; mb < 2; ++mb)
#pragma unroll
      for (int jb = 0; jb < 2; ++jb) S[mb][jb] = (floatx4){0.f, 0.f, 0.f, 0.f};
#pragma unroll
    for (int ks = 0; ks < 8; ++ks) {
      const int chunk = ks * 4 + grp;
#pragma unroll
      for (int jb = 0; jb < 2; ++jb) {
        const int row = jb * 16 + l16;
        half8 kf = *(const half8*)&bK[row * 256 + ((chunk ^ (row & 7)) << 3)];
        S[0][jb] = __builtin_amdgcn_mfma_f32_16x16x32_f16(qf[0][ks], kf, S[0][jb], 0, 0, 0);
        S[1][jb] = __builtin_amdgcn_mfma_f32_16x16x32_f16(qf[1][ks], kf, S[1][jb], 0, 0, 0);
      }
    }

    // ---- raw-S roundtrip; stats + exp in A-layout; pa frags ----
    float alpha[2];
    half8 pa[2];
#pragma unroll
    for (int mb = 0; mb < 2; ++mb) {
#pragma unroll
      for (int jb = 0; jb < 2; ++jb)
#pragma unroll
        for (int r = 0; r < 4; ++r)
          Pw[(grp * 4 + r) * 36 + jb * 16 + l16] = S[mb][jb][r];
      // lane now reads 8 raw scores of query row l16 (cols grp*8..grp*8+7)
      floatx4 u0 = *(const floatx4*)&Pw[l16 * 36 + grp * 8];
      floatx4 u1 = *(const floatx4*)&Pw[l16 * 36 + grp * 8 + 4];
      float mx = fmaxf(fmaxf(fmaxf(u0[0], u0[1]), fmaxf(u0[2], u0[3])),
                       fmaxf(fmaxf(u1[0], u1[1]), fmaxf(u1[2], u1[3])));
      mx = fmaxf(mx, __shfl_xor(mx, 16, 64));
      mx = fmaxf(mx, __shfl_xor(mx, 32, 64));
      const float mnew = fmaxf(m_[mb], mx);
      alpha[mb] = __expf(m_[mb] - mnew);
      m_[mb] = mnew;
      float pe[8];
#pragma unroll
      for (int j = 0; j < 4; ++j) pe[j] = __expf(u0[j] - mnew);
#pragma unroll
      for (int j = 0; j < 4; ++j) pe[4 + j] = __expf(u1[j] - mnew);
      const float ps = ((pe[0] + pe[1]) + (pe[2] + pe[3])) +
                       ((pe[4] + pe[5]) + (pe[6] + pe[7]));
      lsum[mb] = lsum[mb] * alpha[mb] + ps;
      half8 h;
#pragma unroll
      for (int j = 0; j < 8; ++j) h[j] = (f16)pe[j];
      pa[mb] = h;
    }

    // ---- rescale O^T (alpha is per-lane scalar; skip when maxes static) ----
    if (__any(alpha[0] < 1.f) || __any(alpha[1] < 1.f)) {
#pragma unroll
      for (int mb = 0; mb < 2; ++mb)
#pragma unroll
        for (int cb = 0; cb < 16; ++cb) O[mb][cb] *= alpha[mb];
    }

    // ---- O^T += V * P^T : A=V rows (lane l16 = channel), B=pa ----
#pragma unroll
    for (int cb = 0; cb < 16; ++cb) {
      const int c = cb * 16 + l16;
      half8 vf = *(const half8*)&bV[c * 32 + ((grp ^ ((c >> 2) & 3)) << 3)];
      O[0][cb] = __builtin_amdgcn_mfma_f32_16x16x32_f16(vf, pa[0], O[0][cb], 0, 0, 0);
      O[1][cb] = __builtin_amdgcn_mfma_f32_16x16x32_f16(vf, pa[1], O[1][cb], 0, 0, 0);
    }
  }

  // ---- final l reduce across the 4 grp lane-groups of each query row ----
#pragma unroll
  for (int mb = 0; mb < 2; ++mb) {
    lsum[mb] += __shfl_xor(lsum[mb], 16, 64);
    lsum[mb] += __shfl_xor(lsum[mb], 32, 64);
  }
  if (grp == 0) {
    const int base = (b * SPLITS + s) * NDIM + i0;
#pragma unroll
    for (int mb = 0; mb < 2; ++mb) {
      const int i = wave * 32 + mb * 16 + l16;
      pm[base + i] = m_[mb];
      pl[base + i] = lsum[mb];
    }
  }

  // ---- epilogue: direct stores from O^T C-layout ----
  // lane value (mb,cb,r): channel c = cb*16 + grp*4 + r, query i = i0+wq+mb*16+l16
  const size_t pbase = (size_t)(b * SPLITS + s) * CDIM * NDIM;
#pragma unroll
  for (int mb = 0; mb < 2; ++mb) {
    const int i = i0 + wave * 32 + mb * 16 + l16;
#pragma unroll
    for (int cb = 0; cb < 16; ++cb) {
      const int c = cb * 16 + grp * 4;
#pragma unroll
      for (int r = 0; r < 4; ++r)
        pO[pbase + (size_t)(c + r) * NDIM + i] = (f16)O[mb][cb][r];
    }
  }
}

// ---------------------------------------------------------------------------
// Combine 4 split partials: out[b][c][i] = sum_s u_s(i) * O_s[c][i]
// ---------------------------------------------------------------------------
__global__ __launch_bounds__(256) void combine_k(
    const f16* __restrict__ pO, const float* __restrict__ pm,
    const float* __restrict__ pl, float* __restrict__ out) {
  __shared__ float su[SPLITS][64];
  const int b = blockIdx.x >> 6;
  const int i0 = (blockIdx.x & 63) * 64;
  const int t = threadIdx.x;
  if (t < 64) {
    const int i = i0 + t;
    float mv[SPLITS], w[SPLITS];
    float M = -3e38f;
#pragma unroll
    for (int s = 0; s < SPLITS; ++s) {
      mv[s] = pm[(b * SPLITS + s) * NDIM + i];
      M = fmaxf(M, mv[s]);
    }
    float L = 0.f;
#pragma unroll
    for (int s = 0; s < SPLITS; ++s) {
      w[s] = __expf(mv[s] - M);
      L += pl[(b * SPLITS + s) * NDIM + i] * w[s];
    }
    const float invL = 1.0f / L;
#pragma unroll
    for (int s = 0; s < SPLITS; ++s) su[s][t] = w[s] * invL;
  }
  __syncthreads();
#pragma unroll
  for (int it = 0; it < 8; ++it) {
    const int task = t + it * 256;
    const int c = task >> 3, p = (task & 7) * 8;
    float acc[8] = {0.f, 0.f, 0.f, 0.f, 0.f, 0.f, 0.f, 0.f};
#pragma unroll
    for (int s = 0; s < SPLITS; ++s) {
      const f16* src = pO + ((size_t)(b * SPLITS + s) * CDIM + c) * NDIM + i0 + p;
      half8 h = *(const half8*)src;
#pragma unroll
      for (int j = 0; j < 8; ++j) acc[j] += su[s][p + j] * (float)h[j];
    }
    float* dst = out + ((size_t)b * CDIM + c) * NDIM + i0 + p;
    float4 lo = {acc[0], acc[1], acc[2], acc[3]};
    float4 hi = {acc[4], acc[5], acc[6], acc[7]};
    *(float4*)dst = lo;
    *(float4*)(dst + 4) = hi;
  }
}

// ---------------------------------------------------------------------------
extern "C" void kernel_launch(void* const* d_in, const int* in_sizes, int n_in,
                              void* d_out, int out_size, void* d_ws, size_t ws_size,
                              hipStream_t stream) {
  const float* x1 = (const float*)d_in[0];
  const float* x2 = (const float*)d_in[1];
  const float* Wq = (const float*)d_in[2];
  const float* bq = (const float*)d_in[3];
  const float* Wk = (const float*)d_in[4];
  const float* bk = (const float*)d_in[5];
  const float* Wv = (const float*)d_in[6];
  const float* bv = (const float*)d_in[7];
  float* out = (float*)d_out;
  char* ws = (char*)d_ws;
  // 8 MB each
  f16* qtp = (f16*)(ws + 0);
  f16* ktp = (f16*)(ws + 8388608);
  f16* vsp = (f16*)(ws + 16777216);
  f16* xt1 = (f16*)(ws + 25165824);
  f16* xt2 = (f16*)(ws + 33554432);
  f16* whq = (f16*)(ws + 41943040);
  f16* whk = whq + CDIM * CDIM;
  f16* whv = whk + CDIM * CDIM;
  // pO (32 MB) overlays xt1/xt2/wh (dead after proj kernels)
  f16* pO = (f16*)(ws + 25165824);
  float* pm = (float*)(ws + 58720256);
  float* pl = (float*)(ws + 58982400);

  prep_w_k<<<dim3(96), dim3(256), 0, stream>>>(Wq, Wk, Wv, whq, whk, whv);
  transpose_k<<<dim3(NDIM / 64, CDIM / 64, 2 * BATCH), dim3(256), 0, stream>>>(x1, x2, xt1, xt2);
  proj_qk_k<<<dim3(2, 32, 2 * BATCH), dim3(256), 0, stream>>>(xt1, xt2, whq, bq, whk, bk, qtp, ktp);
  proj_v_k<<<dim3(2, 32, BATCH), dim3(256), 0, stream>>>(xt2, whv, bv, vsp);
  flash_k<<<dim3(512), dim3(256), 0, stream>>>(qtp, ktp, vsp, pO, pm, pl);
  combine_k<<<dim3(256), dim3(256), 0, stream>>>(pO, pm, pl, out);
}

// Round 8
// 254.376 us; speedup vs baseline: 2.7804x; 1.0297x over previous
//
#include <hip/hip_runtime.h>

#define BATCH 4
#define CDIM 256
#define NDIM 4096
#define SPLITS 4
#define KSPLIT (NDIM / SPLITS)   // 1024 keys per split
#define JT 32                    // keys per j-tile
#define NTILES (KSPLIT / JT)     // 32

typedef unsigned short u16;
typedef unsigned int u32;
typedef _Float16 f16;
typedef __attribute__((ext_vector_type(8))) _Float16 half8;
typedef __attribute__((ext_vector_type(4))) float floatx4;

__device__ __forceinline__ void load_lds_128(const void* g, void* l) {
  __builtin_amdgcn_global_load_lds(
      (const __attribute__((address_space(1))) u32*)g,
      (__attribute__((address_space(3))) u32*)l, 16, 0, 0);
}

// ---------------------------------------------------------------------------
// W (f32 [C][C]) -> fp16 [C][C], rows stay contraction-contiguous.
// ---------------------------------------------------------------------------
__global__ __launch_bounds__(256) void prep_w_k(
    const float* __restrict__ wq, const float* __restrict__ wk,
    const float* __restrict__ wv, f16* __restrict__ whq,
    f16* __restrict__ whk, f16* __restrict__ whv) {
  const int gid = blockIdx.x * 256 + threadIdx.x;  // 0..24575
  const int a = gid >> 13;
  const int r = gid & 8191;
  const float* src = (a == 0) ? wq : ((a == 1) ? wk : wv);
  f16* dst = (a == 0) ? whq : ((a == 1) ? whk : whv);
  float4 v0 = *(const float4*)(src + r * 8);
  float4 v1 = *(const float4*)(src + r * 8 + 4);
  half8 h;
  h[0] = (f16)v0.x; h[1] = (f16)v0.y; h[2] = (f16)v0.z; h[3] = (f16)v0.w;
  h[4] = (f16)v1.x; h[5] = (f16)v1.y; h[6] = (f16)v1.z; h[7] = (f16)v1.w;
  *(half8*)(dst + r * 8) = h;
}

// ---------------------------------------------------------------------------
// Fused transpose + projection. grid (NDIM/128, BATCH, 3), block 256.
// Block stages x tile [256 c'][128 n] f32 -> f16 LDS (stride 132; 2-way-free
// column reads), then:
//   proj 0: Qt[b][j][c] = sum x1[c'][j] Wq[c][c'] + bq  (A=xt, B=Wq, D[j][c])
//   proj 1: Kt likewise from x2/Wk
//   proj 2: Vs[b][c][j] = sum Wv[c][c'] x2[c'][j] + bv  (A=Wv, B=xt, D[c][j])
// ---------------------------------------------------------------------------
__global__ __launch_bounds__(256, 2) void proj_fused_k(
    const float* __restrict__ x1, const float* __restrict__ x2,
    const f16* __restrict__ whq, const float* __restrict__ bq,
    const f16* __restrict__ whk, const float* __restrict__ bk,
    const f16* __restrict__ whv, const float* __restrict__ bv,
    f16* __restrict__ qt, f16* __restrict__ kt, f16* __restrict__ vsp) {
  __shared__ __align__(16) u16 xt[256 * 132];  // 67584 B
  const int j0 = blockIdx.x * 128;
  const int b = blockIdx.y;
  const int proj = blockIdx.z;
  const float* xs = ((proj == 0) ? x1 : x2) + (size_t)b * CDIM * NDIM;
  const int t = threadIdx.x;
  // ---- stage: thread t loads float4 at (c = flat>>5, n4 = (flat&31)*4) ----
#pragma unroll
  for (int it = 0; it < 32; ++it) {
    const int flat = t + it * 256;       // 0..8191
    const int c = flat >> 5;
    const int n4 = (flat & 31) << 2;
    float4 v = *(const float4*)(xs + (size_t)c * NDIM + j0 + n4);
    union { f16 h[4]; uint2 u; } pk;
    pk.h[0] = (f16)v.x; pk.h[1] = (f16)v.y; pk.h[2] = (f16)v.z; pk.h[3] = (f16)v.w;
    *(uint2*)&xt[c * 132 + n4] = pk.u;
  }
  __syncthreads();
  const int wave = t >> 6, lane = t & 63, l16 = lane & 15, grp = lane >> 4;
  const f16* xth = (const f16*)xt;

  if (proj < 2) {
    // ---- Q/K: wave covers j-range 32 (2 mb) x full 256 c (16 nb) ----
    const f16* w = proj ? whk : whq;
    const float* bias = proj ? bk : bq;
    f16* outp = (proj ? kt : qt) + (size_t)b * NDIM * CDIM;
    floatx4 acc[2][16];
#pragma unroll
    for (int mb = 0; mb < 2; ++mb)
#pragma unroll
      for (int nb = 0; nb < 16; ++nb) acc[mb][nb] = (floatx4){0.f, 0.f, 0.f, 0.f};
#pragma unroll
    for (int ks = 0; ks < 8; ++ks) {
      half8 a[2];
#pragma unroll
      for (int mb = 0; mb < 2; ++mb) {
        const int n = wave * 32 + mb * 16 + l16;
        half8 av;
#pragma unroll
        for (int jj = 0; jj < 8; ++jj)
          av[jj] = xth[(ks * 32 + grp * 8 + jj) * 132 + n];
        a[mb] = av;
      }
#pragma unroll
      for (int nb = 0; nb < 16; ++nb) {
        half8 bb = *(const half8*)(w + (size_t)(nb * 16 + l16) * CDIM + ks * 32 + grp * 8);
        acc[0][nb] = __builtin_amdgcn_mfma_f32_16x16x32_f16(a[0], bb, acc[0][nb], 0, 0, 0);
        acc[1][nb] = __builtin_amdgcn_mfma_f32_16x16x32_f16(a[1], bb, acc[1][nb], 0, 0, 0);
      }
    }
#pragma unroll
    for (int nb = 0; nb < 16; ++nb) {
      const int c = nb * 16 + l16;
      const float bvv = bias[c];
#pragma unroll
      for (int mb = 0; mb < 2; ++mb) {
        const int jbase = j0 + wave * 32 + mb * 16 + grp * 4;
#pragma unroll
        for (int r = 0; r < 4; ++r)
          outp[(size_t)(jbase + r) * CDIM + c] = (f16)(acc[mb][nb][r] + bvv);
      }
    }
  } else {
    // ---- V: wave covers c-half 128 (8 mb) x j-half 64 (4 nb) ----
    f16* outp = vsp + (size_t)b * CDIM * NDIM;
    const int cw = (wave & 1) * 128;
    const int jw = (wave >> 1) * 64;
    floatx4 acc[8][4];
#pragma unroll
    for (int mb = 0; mb < 8; ++mb)
#pragma unroll
      for (int nb = 0; nb < 4; ++nb) acc[mb][nb] = (floatx4){0.f, 0.f, 0.f, 0.f};
#pragma unroll
    for (int ks = 0; ks < 8; ++ks) {
      half8 a[8];
#pragma unroll
      for (int mb = 0; mb < 8; ++mb)
        a[mb] = *(const half8*)(whv + (size_t)(cw + mb * 16 + l16) * CDIM + ks * 32 + grp * 8);
#pragma unroll
      for (int nb = 0; nb < 4; ++nb) {
        const int n = jw + nb * 16 + l16;
        half8 bv8;
#pragma unroll
        for (int jj = 0; jj < 8; ++jj)
          bv8[jj] = xth[(ks * 32 + grp * 8 + jj) * 132 + n];
#pragma unroll
        for (int mb = 0; mb < 8; ++mb)
          acc[mb][nb] = __builtin_amdgcn_mfma_f32_16x16x32_f16(a[mb], bv8, acc[mb][nb], 0, 0, 0);
      }
    }
#pragma unroll
    for (int mb = 0; mb < 8; ++mb)
#pragma unroll
      for (int r = 0; r < 4; ++r) {
        const int c = cw + mb * 16 + grp * 4 + r;
        const float bvv = bv[c];
#pragma unroll
        for (int nb = 0; nb < 4; ++nb) {
          const int j = j0 + jw + nb * 16 + l16;
          outp[(size_t)c * NDIM + j] = (f16)(acc[mb][nb][r] + bvv);
        }
      }
  }
}

// ---------------------------------------------------------------------------
// Flash attention partial (r7 interior + f16/stride-40 P scratch):
//  - raw-S f16 LDS roundtrip; stats in A-layout (in-lane tree + xor16/32)
//  - PV transposed: O^T[c][i]; alpha per-lane; direct epilogue stores
//  - K/V double-buffered, ONE barrier per tile, prefetch-after-barrier
// Grid 512 = 32 q-tiles x (4 b x 4 split); 4 waves, 32 q/wave, 2 blocks/CU.
// LDS: dbuf 2x32 KB + P 16x40 f16/wave = 69.1 KB.
// ---------------------------------------------------------------------------
__global__ __launch_bounds__(256, 2) void flash_k(
    const f16* __restrict__ qt, const f16* __restrict__ kt,
    const f16* __restrict__ vs, f16* __restrict__ pO,
    float* __restrict__ pm, float* __restrict__ pl) {
  __shared__ __align__(16) u16 smem[32768 + 2560];  // 64 KB dbuf + 5120 B P
  const int bx = blockIdx.x;
  const int c16 = bx & 15;                   // XCD-pinned (b,s)
  const int b = c16 >> 2, s = c16 & 3;
  const int i0 = (bx >> 4) * 128;
  const int jwin = s * KSPLIT;
  const f16* Q = qt + (size_t)b * NDIM * CDIM;
  const f16* K = kt + (size_t)b * NDIM * CDIM;
  const f16* V = vs + (size_t)b * CDIM * NDIM;
  const int tid = threadIdx.x;
  const int wave = tid >> 6, lane = tid & 63, l16 = lane & 15, grp = lane >> 4;
  f16* Pw = (f16*)(smem + 32768) + wave * (16 * 40);  // 16 rows x 40 f16

  // persistent Q frags: 2 m-blocks of 16 q
  half8 qf[2][8];
#pragma unroll
  for (int mb = 0; mb < 2; ++mb)
#pragma unroll
    for (int ks = 0; ks < 8; ++ks)
      qf[mb][ks] = *(const half8*)(Q + (size_t)(i0 + wave * 32 + mb * 16 + l16) * CDIM +
                                   ks * 32 + grp * 8);

  floatx4 O[2][16];  // O^T: row=channel-local grp*4+r, col=query l16
#pragma unroll
  for (int mb = 0; mb < 2; ++mb)
#pragma unroll
    for (int cb = 0; cb < 16; ++cb) O[mb][cb] = (floatx4){0.f, 0.f, 0.f, 0.f};
  float m_[2] = {-1e30f, -1e30f};
  float lsum[2] = {0.f, 0.f};

  const int kr2 = lane >> 5, kp = lane & 31;   // K staging: 2 rows/instr
  const int vrow = lane >> 2, vp = lane & 3;   // V staging: 16 rows/instr

#define STAGE(J0, BUF)                                                         \
  {                                                                            \
    u16* sK = smem + (BUF) * 16384;                                            \
    u16* sV = sK + 8192;                                                       \
    _Pragma("unroll") for (int it = 0; it < 4; ++it) {                         \
      const int row = wave * 8 + it * 2 + kr2;                                 \
      const int g = kp ^ (row & 7);                                            \
      load_lds_128(K + (size_t)((J0) + row) * CDIM + g * 8,                    \
                   &sK[(wave * 8 + it * 2) * 256]);                            \
    }                                                                          \
    _Pragma("unroll") for (int it = 0; it < 4; ++it) {                         \
      const int c = wave * 64 + it * 16 + vrow;                                \
      const int g = vp ^ ((c >> 2) & 3);                                       \
      load_lds_128(V + (size_t)c * NDIM + (J0) + g * 8,                        \
                   &sV[(wave * 64 + it * 16) * 32]);                           \
    }                                                                          \
  }

  STAGE(jwin, 0)

  for (int tt = 0; tt < NTILES; ++tt) {
    __syncthreads();  // drains prefetch(tt); frees buffer (tt+1)&1
    if (tt + 1 < NTILES) STAGE(jwin + (tt + 1) * JT, (tt + 1) & 1)
    u16* bK = smem + (tt & 1) * 16384;
    u16* bV = bK + 8192;

    // ---- S = Q K^T (C-layout: row=query grp*4+r, col=key l16) ----
    floatx4 S[2][2];
#pragma unroll
    for (int mb = 0; mb < 2; ++mb)
#pragma unroll
      for (int jb = 0; jb < 2; ++jb) S[mb][jb] = (floatx4){0.f, 0.f, 0.f, 0.f};
#pragma unroll
    for (int ks = 0; ks < 8; ++ks) {
      const int chunk = ks * 4 + grp;
#pragma unroll
      for (int jb = 0; jb < 2; ++jb) {
        const int row = jb * 16 + l16;
        half8 kf = *(const half8*)&bK[row * 256 + ((chunk ^ (row & 7)) << 3)];
        S[0][jb] = __builtin_amdgcn_mfma_f32_16x16x32_f16(qf[0][ks], kf, S[0][jb], 0, 0, 0);
        S[1][jb] = __builtin_amdgcn_mfma_f32_16x16x32_f16(qf[1][ks], kf, S[1][jb], 0, 0, 0);
      }
    }

    // ---- raw-S (f16) roundtrip; stats + exp in A-layout; pa frags ----
    float alpha[2];
    half8 pa[2];
#pragma unroll
    for (int mb = 0; mb < 2; ++mb) {
#pragma unroll
      for (int jb = 0; jb < 2; ++jb)
#pragma unroll
        for (int r = 0; r < 4; ++r)
          Pw[(grp * 4 + r) * 40 + jb * 16 + l16] = (f16)S[mb][jb][r];
      // lane reads 8 raw scores of query row l16 (cols grp*8..grp*8+7)
      half8 rawh = *(const half8*)&Pw[l16 * 40 + grp * 8];
      float u[8];
#pragma unroll
      for (int j = 0; j < 8; ++j) u[j] = (float)rawh[j];
      float mx = fmaxf(fmaxf(fmaxf(u[0], u[1]), fmaxf(u[2], u[3])),
                       fmaxf(fmaxf(u[4], u[5]), fmaxf(u[6], u[7])));
      mx = fmaxf(mx, __shfl_xor(mx, 16, 64));
      mx = fmaxf(mx, __shfl_xor(mx, 32, 64));
      const float mnew = fmaxf(m_[mb], mx);
      alpha[mb] = __expf(m_[mb] - mnew);
      m_[mb] = mnew;
      float pe[8];
#pragma unroll
      for (int j = 0; j < 8; ++j) pe[j] = __expf(u[j] - mnew);
      const float ps = ((pe[0] + pe[1]) + (pe[2] + pe[3])) +
                       ((pe[4] + pe[5]) + (pe[6] + pe[7]));
      lsum[mb] = lsum[mb] * alpha[mb] + ps;
      half8 h;
#pragma unroll
      for (int j = 0; j < 8; ++j) h[j] = (f16)pe[j];
      pa[mb] = h;
    }

    // ---- rescale O^T (skip when maxes static) ----
    if (__any(alpha[0] < 1.f) || __any(alpha[1] < 1.f)) {
#pragma unroll
      for (int mb = 0; mb < 2; ++mb)
#pragma unroll
        for (int cb = 0; cb < 16; ++cb) O[mb][cb] *= alpha[mb];
    }

    // ---- O^T += V * P^T : A=V rows (lane l16 = channel), B=pa ----
#pragma unroll
    for (int cb = 0; cb < 16; ++cb) {
      const int c = cb * 16 + l16;
      half8 vf = *(const half8*)&bV[c * 32 + ((grp ^ ((c >> 2) & 3)) << 3)];
      O[0][cb] = __builtin_amdgcn_mfma_f32_16x16x32_f16(vf, pa[0], O[0][cb], 0, 0, 0);
      O[1][cb] = __builtin_amdgcn_mfma_f32_16x16x32_f16(vf, pa[1], O[1][cb], 0, 0, 0);
    }
  }

  // ---- final l reduce across the 4 grp lane-groups ----
#pragma unroll
  for (int mb = 0; mb < 2; ++mb) {
    lsum[mb] += __shfl_xor(lsum[mb], 16, 64);
    lsum[mb] += __shfl_xor(lsum[mb], 32, 64);
  }
  if (grp == 0) {
    const int base = (b * SPLITS + s) * NDIM + i0;
#pragma unroll
    for (int mb = 0; mb < 2; ++mb) {
      const int i = wave * 32 + mb * 16 + l16;
      pm[base + i] = m_[mb];
      pl[base + i] = lsum[mb];
    }
  }

  // ---- epilogue: direct stores from O^T C-layout ----
  const size_t pbase = (size_t)(b * SPLITS + s) * CDIM * NDIM;
#pragma unroll
  for (int mb = 0; mb < 2; ++mb) {
    const int i = i0 + wave * 32 + mb * 16 + l16;
#pragma unroll
    for (int cb = 0; cb < 16; ++cb) {
      const int c = cb * 16 + grp * 4;
#pragma unroll
      for (int r = 0; r < 4; ++r)
        pO[pbase + (size_t)(c + r) * NDIM + i] = (f16)O[mb][cb][r];
    }
  }
}

// ---------------------------------------------------------------------------
// Combine 4 split partials: out[b][c][i] = sum_s u_s(i) * O_s[c][i]
// ---------------------------------------------------------------------------
__global__ __launch_bounds__(256) void combine_k(
    const f16* __restrict__ pO, const float* __restrict__ pm,
    const float* __restrict__ pl, float* __restrict__ out) {
  __shared__ float su[SPLITS][64];
  const int b = blockIdx.x >> 6;
  const int i0 = (blockIdx.x & 63) * 64;
  const int t = threadIdx.x;
  if (t < 64) {
    const int i = i0 + t;
    float mv[SPLITS], w[SPLITS];
    float M = -3e38f;
#pragma unroll
    for (int s = 0; s < SPLITS; ++s) {
      mv[s] = pm[(b * SPLITS + s) * NDIM + i];
      M = fmaxf(M, mv[s]);
    }
    float L = 0.f;
#pragma unroll
    for (int s = 0; s < SPLITS; ++s) {
      w[s] = __expf(mv[s] - M);
      L += pl[(b * SPLITS + s) * NDIM + i] * w[s];
    }
    const float invL = 1.0f / L;
#pragma unroll
    for (int s = 0; s < SPLITS; ++s) su[s][t] = w[s] * invL;
  }
  __syncthreads();
#pragma unroll
  for (int it = 0; it < 8; ++it) {
    const int task = t + it * 256;
    const int c = task >> 3, p = (task & 7) * 8;
    float acc[8] = {0.f, 0.f, 0.f, 0.f, 0.f, 0.f, 0.f, 0.f};
#pragma unroll
    for (int s = 0; s < SPLITS; ++s) {
      const f16* src = pO + ((size_t)(b * SPLITS + s) * CDIM + c) * NDIM + i0 + p;
      half8 h = *(const half8*)src;
#pragma unroll
      for (int j = 0; j < 8; ++j) acc[j] += su[s][p + j] * (float)h[j];
    }
    float* dst = out + ((size_t)b * CDIM + c) * NDIM + i0 + p;
    float4 lo = {acc[0], acc[1], acc[2], acc[3]};
    float4 hi = {acc[4], acc[5], acc[6], acc[7]};
    *(float4*)dst = lo;
    *(float4*)(dst + 4) = hi;
  }
}

// ---------------------------------------------------------------------------
extern "C" void kernel_launch(void* const* d_in, const int* in_sizes, int n_in,
                              void* d_out, int out_size, void* d_ws, size_t ws_size,
                              hipStream_t stream) {
  const float* x1 = (const float*)d_in[0];
  const float* x2 = (const float*)d_in[1];
  const float* Wq = (const float*)d_in[2];
  const float* bq = (const float*)d_in[3];
  const float* Wk = (const float*)d_in[4];
  const float* bk = (const float*)d_in[5];
  const float* Wv = (const float*)d_in[6];
  const float* bv = (const float*)d_in[7];
  float* out = (float*)d_out;
  char* ws = (char*)d_ws;
  f16* qtp = (f16*)(ws + 0);
  f16* ktp = (f16*)(ws + 8388608);
  f16* vsp = (f16*)(ws + 16777216);
  f16* whq = (f16*)(ws + 41943040);
  f16* whk = whq + CDIM * CDIM;
  f16* whv = whk + CDIM * CDIM;
  f16* pO = (f16*)(ws + 25165824);   // 32 MB region (dead xt space)
  float* pm = (float*)(ws + 58720256);
  float* pl = (float*)(ws + 58982400);

  prep_w_k<<<dim3(96), dim3(256), 0, stream>>>(Wq, Wk, Wv, whq, whk, whv);
  proj_fused_k<<<dim3(NDIM / 128, BATCH, 3), dim3(256), 0, stream>>>(
      x1, x2, whq, bq, whk, bk, whv, bv, qtp, ktp, vsp);
  flash_k<<<dim3(512), dim3(256), 0, stream>>>(qtp, ktp, vsp, pO, pm, pl);
  combine_k<<<dim3(256), dim3(256), 0, stream>>>(pO, pm, pl, out);
}